// Round 4
// baseline (313.484 us; speedup 1.0000x reference)
//
#include <hip/hip_runtime.h>
#include <hip/hip_bf16.h>

#define Bn 1024
#define Lr 320
#define Dd 128
#define Ee 8
#define Pp 96

typedef short bf16x8 __attribute__((ext_vector_type(8)));
typedef float f32x4 __attribute__((ext_vector_type(4)));
typedef unsigned u32x4 __attribute__((ext_vector_type(4)));
typedef unsigned short u16;

__device__ __forceinline__ float cdf_f(float v) {
    return 0.5f * (1.0f + erff(v * 0.70710678118654752f));
}
__device__ __forceinline__ float softplus_f(float x) {
    return fmaxf(x, 0.0f) + log1pf(expf(-fabsf(x)));
}
__device__ __forceinline__ u16 f2bf(float f) {
    unsigned int u = __float_as_uint(f);
    return (u16)((u + 0x7fffu + ((u >> 16) & 1u)) >> 16);
}
__device__ __forceinline__ float bf2f(u16 u) {
    return __uint_as_float(((unsigned int)u) << 16);
}

// async global->LDS, 16 B per lane; LDS dest is wave-uniform base + lane*16.
__device__ __forceinline__ void gload16(const void* g, void* l) {
    __builtin_amdgcn_global_load_lds(
        (const __attribute__((address_space(1))) void*)g,
        (__attribute__((address_space(3))) void*)l, 16, 0, 0);
}

// expert_w fp32 [e][l][p] -> W_t bf16 [e][p][l] (l contiguous). 0.5 MB, L2-resident.
__global__ __launch_bounds__(256) void transpose_w(
    const float* __restrict__ ew, u16* __restrict__ wt)
{
    __shared__ float tile[Pp * 33];
    const int e  = blockIdx.x;       // 0..7
    const int l0 = blockIdx.y * 32;  // 0..288
    const int t  = threadIdx.x;
    #pragma unroll
    for (int i = 0; i < 12; ++i) {
        const int idx = t + 256 * i;            // 0..3071
        const int lp = idx / 96, p = idx - 96 * lp;
        tile[p * 33 + lp] = ew[((size_t)e * Lr + l0 + lp) * Pp + p];
    }
    __syncthreads();
    #pragma unroll
    for (int i = 0; i < 6; ++i) {
        const int g = t + 256 * i;              // 0..1535
        const int p = g >> 4, l2 = (g & 15) * 2;
        const unsigned pk = (unsigned)f2bf(tile[p * 33 + l2]) |
                            ((unsigned)f2bf(tile[p * 33 + l2 + 1]) << 16);
        *(unsigned*)&wt[((size_t)(e * Pp + p)) * Lr + l0 + l2] = pk;
    }
}

// Fused per-b kernel: one block per b, 512 threads (8 waves), 1 block/CU.
// Phase 1: stream x[b] once -> g[b,:] (fp32, bit-identical order to old
//          g_kernel) + bf16 x^T fragment image in LDS (XOR-swizzled).
// Gate   : wave 0 reruns old gate_kernel code against LDS g; publishes
//          (e0,e1,g0,g1); load/importance atomics to accum.
// Phase 2: round-3-verified MFMA loop; W dbuf via global_load_lds (same
//          swizzle scheme), B-fragment = one ds_read_b128 from XT.
__global__ __launch_bounds__(512) void fused_kernel(
    const float* __restrict__ x, const u16* __restrict__ wt,
    const float* __restrict__ expert_b, const float* __restrict__ noise,
    const float* __restrict__ w_gate, const float* __restrict__ w_noise,
    const float* __restrict__ start_w, const float* __restrict__ start_b,
    float* __restrict__ accum, float* __restrict__ out)
{
    __shared__ __align__(16) unsigned XT[10 * 128 * 16];   // 80 KB bf16 x^T
    __shared__ __align__(16) unsigned Ws[2][192 * 16];     // 24 KB W dbuf
    __shared__ __align__(8)  float gl[Lr];                 // g[b,:]
    __shared__ float gsh[2];
    __shared__ int   ish[2];

    const int b    = blockIdx.x;
    const int t    = threadIdx.x;
    const int lane = t & 63;
    const int wv   = t >> 6;          // 0..7

    // ---------------- phase 1: x stream + g + XT pack ----------------
    const float sb = start_b[0];
    const int f8 = t & 7;             // d-octant (matches old g_kernel)
    float4 sw[4];
    #pragma unroll
    for (int j = 0; j < 4; ++j) sw[j] = ((const float4*)start_w)[f8 + 8 * j];

    #pragma unroll
    for (int pass = 0; pass < 3; ++pass) {
        const int pi = (t >> 3) + 64 * pass;   // row-pair index 0..159
        if (pi < 160) {
            const float* r0 = x + ((size_t)b * Lr + 2 * pi) * Dd;
            float4 v0[4], v1[4];
            #pragma unroll
            for (int j = 0; j < 4; ++j) {
                v0[j] = ((const float4*)r0)[f8 + 8 * j];
                v1[j] = ((const float4*)(r0 + Dd))[f8 + 8 * j];
            }
            float a0 = 0.f, a1 = 0.f;
            #pragma unroll
            for (int j = 0; j < 4; ++j) {
                a0 += v0[j].x * sw[j].x + v0[j].y * sw[j].y +
                      v0[j].z * sw[j].z + v0[j].w * sw[j].w;
                a1 += v1[j].x * sw[j].x + v1[j].y * sw[j].y +
                      v1[j].z * sw[j].z + v1[j].w * sw[j].w;
            }
            #pragma unroll
            for (int off = 1; off <= 4; off <<= 1) {
                a0 += __shfl_xor(a0, off);
                a1 += __shfl_xor(a1, off);
            }
            if (f8 == 0) { gl[2 * pi] = a0 + sb; gl[2 * pi + 1] = a1 + sb; }
            // pack (l even, l odd) bf16 pairs into XT[tile][d][k2 ^ sigma(d)]
            const int tt = pi >> 4, k2 = pi & 15;
            #pragma unroll
            for (int j = 0; j < 4; ++j) {
                const float* p0 = (const float*)&v0[j];
                const float* p1 = (const float*)&v1[j];
                #pragma unroll
                for (int jj = 0; jj < 4; ++jj) {
                    const int d  = 4 * (f8 + 8 * j) + jj;
                    const int sg = ((d ^ (d >> 2)) & 3) << 2;
                    XT[(tt * 128 + d) * 16 + (k2 ^ sg)] =
                        (unsigned)f2bf(p0[jj]) | ((unsigned)f2bf(p1[jj]) << 16);
                }
            }
        }
    }
    __syncthreads();

    // ---------------- gate (wave 0 only, code == old gate_kernel) -----
    if (t < 64) {
        const int e = t & 7, seg = t >> 3;
        float pc = 0.f, pn = 0.f;
        #pragma unroll 8
        for (int i = 0; i < 40; ++i) {
            const int l = seg * 40 + i;
            const float gv = gl[l];
            pc += gv * w_gate[l * Ee + e];
            pn += gv * w_noise[l * Ee + e];
        }
        #pragma unroll
        for (int off = 8; off <= 32; off <<= 1) {
            pc += __shfl_xor(pc, off);
            pn += __shfl_xor(pn, off);
        }
        const float sdv   = softplus_f(pn) + 0.01f;   // NOISE_EPS
        float       c     = pc;
        const float nz    = noise[b * Ee + e];
        const float noisy = c + nz * sdv;

        float nv[8];
        #pragma unroll
        for (int j = 0; j < 8; ++j) nv[j] = __shfl(noisy, j);

        int i0 = -1, i1 = -1;
        float v0 = -INFINITY, v1 = -INFINITY, v2 = -INFINITY;
        #pragma unroll
        for (int i = 0; i < 8; ++i) if (nv[i] > v0) { v0 = nv[i]; i0 = i; }
        #pragma unroll
        for (int i = 0; i < 8; ++i) if (i != i0 && nv[i] > v1) { v1 = nv[i]; i1 = i; }
        #pragma unroll
        for (int i = 0; i < 8; ++i) if (i != i0 && i != i1 && nv[i] > v2) { v2 = nv[i]; }

        const float ex1 = expf(v1 - v0);
        const float den = 1.f + ex1;
        const float gate_e = (e == i0) ? (1.f / den) : ((e == i1) ? (ex1 / den) : 0.f);

        if (isnan(c)) c = 0.f;
        const float pr = (noisy > v2) ? cdf_f((c - v2) / sdv) : cdf_f((c - v1) / sdv);

        if (t == 0) {
            ish[0] = i0; ish[1] = i1;
            gsh[0] = 1.f / den; gsh[1] = ex1 / den;
        }
        if (t < 8) {
            atomicAdd(&accum[8 + e], gate_e);  // importance
            atomicAdd(&accum[e], pr);          // load
        }
    }
    __syncthreads();

    // ---------------- phase 2: MFMA ----------------------------------
    const int e0 = ish[0], e1 = ish[1];
    const float g0 = gsh[0], g1 = gsh[1];
    const u16* w0r = wt + (size_t)e0 * Pp * Lr;
    const u16* w1r = wt + (size_t)e1 * Pp * Lr;

    const int wrow = lane >> 2, wq = lane & 3;
    auto STAGE_W = [&](int buf, int l0) {
        #pragma unroll
        for (int i = 0; i < 2; ++i) {
            const int c = wv + 8 * i;                      // chunks 0..11
            if (c < 12) {
                const int r  = 16 * c + wrow;              // 0..191
                const int dw = (4 * wq) ^ ((r & 3) << 2);  // swizzled src dword
                const u16* src = (c < 6) ? (w0r + (size_t)r * Lr)
                                         : (w1r + (size_t)(r - 96) * Lr);
                gload16(src + l0 + 2 * dw, (void*)&Ws[buf][c * 256]);
            }
        }
    };

    const int quad = lane >> 4, r16 = lane & 15;
    const int xdw  = 4 * (quad ^ ((r16 ^ (r16 >> 2)) & 3));  // XT read swizzle
    const int wdw  = (4 * quad) ^ ((r16 & 3) << 2);          // Ws read swizzle
    const int xrow = (16 * wv + r16) * 16;                   // d-row base (dwords)

    f32x4 a0[6], a1[6];
    #pragma unroll
    for (int m = 0; m < 6; ++m) {
        a0[m] = (f32x4){0.f, 0.f, 0.f, 0.f};
        a1[m] = (f32x4){0.f, 0.f, 0.f, 0.f};
    }

    union UF { u32x4 q; bf16x8 v; };

    STAGE_W(0, 0);
    __syncthreads();
    int cur = 0;
    for (int kt = 0; kt < 10; ++kt) {
        if (kt < 9) STAGE_W(cur ^ 1, 32 * (kt + 1));
        UF xf;
        xf.q = *(const u32x4*)&XT[kt * 2048 + xrow + xdw];
        #pragma unroll
        for (int m = 0; m < 6; ++m) {
            UF f0, f1;
            f0.q = *(const u32x4*)&Ws[cur][(16 * m + r16) * 16 + wdw];
            f1.q = *(const u32x4*)&Ws[cur][(96 + 16 * m + r16) * 16 + wdw];
            a0[m] = __builtin_amdgcn_mfma_f32_16x16x32_bf16(f0.v, xf.v, a0[m], 0, 0, 0);
            a1[m] = __builtin_amdgcn_mfma_f32_16x16x32_bf16(f1.v, xf.v, a1[m], 0, 0, 0);
        }
        __syncthreads();
        cur ^= 1;
    }

    // epilogue: fp32 combine + bias. C/D layout: col(d)=r16, row(p)=4*quad+reg
    const int d = 16 * wv + r16;
    const float* eb0 = expert_b + (size_t)e0 * Pp * Dd;
    const float* eb1 = expert_b + (size_t)e1 * Pp * Dd;
    #pragma unroll
    for (int m = 0; m < 6; ++m) {
        #pragma unroll
        for (int r = 0; r < 4; ++r) {
            const int p = 16 * m + 4 * quad + r;
            out[((size_t)b * Pp + p) * Dd + d] =
                g0 * (a0[m][r] + eb0[p * Dd + d]) +
                g1 * (a1[m][r] + eb1[p * Dd + d]);
        }
    }
}

__global__ void loss_kernel(const float* __restrict__ accum,
                            float* __restrict__ out_scalars)
{
    if (threadIdx.x == 0) {
        float lo[8], im[8];
        #pragma unroll
        for (int i = 0; i < 8; ++i) { lo[i] = accum[i]; im[i] = accum[8 + i]; }
        float ml = 0.f, mi = 0.f;
        #pragma unroll
        for (int i = 0; i < 8; ++i) { ml += lo[i]; mi += im[i]; }
        ml *= 0.125f; mi *= 0.125f;
        float sl = 0.f, si = 0.f;
        #pragma unroll
        for (int i = 0; i < 8; ++i) {
            const float dl = lo[i] - ml, di = im[i] - mi;
            sl += dl * dl; si += di * di;
        }
        const float cvl = (sl / 7.f) / (ml * ml + 1e-10f);
        const float cvi = (si / 7.f) / (mi * mi + 1e-10f);
        out_scalars[0] = 0.01f * (cvi + cvl);
        out_scalars[1] = 0.0f;
    }
}

extern "C" void kernel_launch(void* const* d_in, const int* in_sizes, int n_in,
                              void* d_out, int out_size, void* d_ws, size_t ws_size,
                              hipStream_t stream)
{
    const float* x        = (const float*)d_in[0];
    // d_in[1] = x_mark_enc (unused)
    const float* noise    = (const float*)d_in[2];
    const float* start_w  = (const float*)d_in[3];
    const float* start_b  = (const float*)d_in[4];
    const float* w_gate   = (const float*)d_in[5];
    const float* w_noise  = (const float*)d_in[6];
    const float* expert_w = (const float*)d_in[7];
    const float* expert_b = (const float*)d_in[8];
    float* out            = (float*)d_out;

    float* accum = (float*)d_ws;                 // 16 f
    u16*   wt    = (u16*)((char*)d_ws + 256);    // 8*96*320 bf16

    hipMemsetAsync(accum, 0, 16 * sizeof(float), stream);
    hipLaunchKernelGGL(transpose_w, dim3(Ee, Lr / 32), dim3(256), 0, stream,
                       expert_w, wt);
    hipLaunchKernelGGL(fused_kernel, dim3(Bn), dim3(512), 0, stream,
                       x, wt, expert_b, noise, w_gate, w_noise,
                       start_w, start_b, accum, out);
    hipLaunchKernelGGL(loss_kernel, dim3(1), dim3(64), 0, stream,
                       accum, out + (size_t)Bn * Pp * Dd);
}